// Round 1
// baseline (44.539 us; speedup 1.0000x reference)
//
#include <hip/hip_runtime.h>

#define BATCH   1024
#define IDIM    4096
#define NLUTS   16384
#define TPB     256
#define NT      4                 // n's per thread
#define NPB     (TPB * NT)        // 1024 n per block
#define NBLK_N  (NLUTS / NPB)     // 16
#define BTILE   16                // batch rows per block
#define NBLK_B  (BATCH / BTILE)   // 64
#define GRID    (NBLK_N * NBLK_B) // 1024

__global__ __launch_bounds__(TPB, 4)
void lut_fused(const float* __restrict__ x,
               const float* __restrict__ w,
               const float* __restrict__ wcomp,
               const int*   __restrict__ indices,
               float* __restrict__ out)
{
    __shared__ float xs[2][IDIM];   // double-buffered x row (2 x 16 KB)

    // XCD-aware swizzle: blockIdx%8 == XCD (round-robin dispatch). Map each
    // XCD to a contiguous chunk of b-ranges so the x rows it stages stay
    // resident in its private L2 (8 b-ranges x 16 rows x 16KB = 2 MiB/XCD).
    int id    = blockIdx.x;
    int swz   = (id & 7) * (GRID / 8) + (id >> 3);
    int b_blk = swz / NBLK_N;
    int n_blk = swz % NBLK_N;

    int t  = threadIdx.x;
    int n0 = n_blk * NPB + t * NT;   // 4 consecutive n's for this thread
    int b0 = b_blk * BTILE;

    // ---- per-thread LUT indices: ix[q][i] = indices[i][n0+q] ----
    int ix[NT][4];
#pragma unroll
    for (int i = 0; i < 4; ++i) {
        int4 v = *reinterpret_cast<const int4*>(indices + i * NLUTS + n0);
        ix[0][i] = v.x; ix[1][i] = v.y; ix[2][i] = v.z; ix[3][i] = v.w;
    }

    // ---- per-thread monomial coefficients a[q][mask] ----
    // s_j = sigmoid(w_j - wc_j); p[c] = s[15-c]; butterfly (p0,p1)->(p1,p0-p1)
    // per bit turns the {xr, 1-xr} tensor contraction into a pure multilinear
    // polynomial: result = sum_mask a[mask] * prod_{bit bb in mask} xr_{3-bb}.
    float a[NT][16];
#pragma unroll
    for (int q = 0; q < NT; ++q) {
        int n = n0 + q;
        float p[16];
#pragma unroll
        for (int k = 0; k < 4; ++k) {
            float4 wv = *reinterpret_cast<const float4*>(w     + (size_t)n * 16 + k * 4);
            float4 cv = *reinterpret_cast<const float4*>(wcomp + (size_t)n * 16 + k * 4);
            p[15 - (4 * k + 0)] = 1.f / (1.f + __expf(cv.x - wv.x));
            p[15 - (4 * k + 1)] = 1.f / (1.f + __expf(cv.y - wv.y));
            p[15 - (4 * k + 2)] = 1.f / (1.f + __expf(cv.z - wv.z));
            p[15 - (4 * k + 3)] = 1.f / (1.f + __expf(cv.w - wv.w));
        }
#pragma unroll
        for (int s = 8; s >= 1; s >>= 1) {
#pragma unroll
            for (int m = 0; m < 16; ++m) {
                if ((m & s) == 0) {
                    float t0 = p[m];
                    p[m]     = p[m + s];
                    p[m + s] = t0 - p[m + s];
                }
            }
        }
#pragma unroll
        for (int m = 0; m < 16; ++m) a[q][m] = p[m];
    }

    // ---- prologue: stage x[b0] into buffer 0 ----
    {
        const float* xrow = x + (size_t)b0 * IDIM;
#pragma unroll
        for (int k = 0; k < 4; ++k) {
            float4 r = *reinterpret_cast<const float4*>(xrow + (k * TPB + t) * 4);
            *reinterpret_cast<float4*>(&xs[0][(k * TPB + t) * 4]) = r;
        }
    }
    __syncthreads();

    // ---- main loop over the batch tile ----
    for (int bi = 0; bi < BTILE; ++bi) {
        int  cur  = bi & 1;
        bool more = (bi + 1 < BTILE);

        // issue next row's loads early (T14: HBM latency hides under compute)
        float4 r[4];
        if (more) {
            const float* xrow = x + (size_t)(b0 + bi + 1) * IDIM;
#pragma unroll
            for (int k = 0; k < 4; ++k)
                r[k] = *reinterpret_cast<const float4*>(xrow + (k * TPB + t) * 4);
        }

        float res[NT];
#pragma unroll
        for (int q = 0; q < NT; ++q) {
            float xv0 = xs[cur][ix[q][0]];
            float xv1 = xs[cur][ix[q][1]];
            float xv2 = xs[cur][ix[q][2]];
            float xv3 = xs[cur][ix[q][3]];
            // 15-FMA multilinear Horner: bit0<->xr3, bit1<->xr2, bit2<->xr1, bit3<->xr0
            float h0 = fmaf(xv3, a[q][1],  a[q][0]);
            float h1 = fmaf(xv3, a[q][3],  a[q][2]);
            float h2 = fmaf(xv3, a[q][5],  a[q][4]);
            float h3 = fmaf(xv3, a[q][7],  a[q][6]);
            float h4 = fmaf(xv3, a[q][9],  a[q][8]);
            float h5 = fmaf(xv3, a[q][11], a[q][10]);
            float h6 = fmaf(xv3, a[q][13], a[q][12]);
            float h7 = fmaf(xv3, a[q][15], a[q][14]);
            float g0 = fmaf(xv2, h1, h0);
            float g1 = fmaf(xv2, h3, h2);
            float g2 = fmaf(xv2, h5, h4);
            float g3 = fmaf(xv2, h7, h6);
            float f0 = fmaf(xv1, g1, g0);
            float f1 = fmaf(xv1, g3, g2);
            res[q] = fmaf(xv0, f1, f0);
        }

        // coalesced float4 store: out[b0+bi][n0 .. n0+3]
        float4 o;
        o.x = res[0]; o.y = res[1]; o.z = res[2]; o.w = res[3];
        *reinterpret_cast<float4*>(out + (size_t)(b0 + bi) * NLUTS + n0) = o;

        // write next row into the other buffer (vmcnt wait lands here, after compute)
        if (more) {
            int nxt = cur ^ 1;
#pragma unroll
            for (int k = 0; k < 4; ++k)
                *reinterpret_cast<float4*>(&xs[nxt][(k * TPB + t) * 4]) = r[k];
        }
        __syncthreads();
    }
}

extern "C" void kernel_launch(void* const* d_in, const int* in_sizes, int n_in,
                              void* d_out, int out_size, void* d_ws, size_t ws_size,
                              hipStream_t stream) {
    const float* x   = (const float*)d_in[0];
    const float* w   = (const float*)d_in[1];
    const float* wc  = (const float*)d_in[2];
    const int*   idx = (const int*)d_in[3];
    float*       out = (float*)d_out;

    lut_fused<<<dim3(GRID), dim3(TPB), 0, stream>>>(x, w, wc, idx, out);
}